// Round 14
// baseline (530.779 us; speedup 1.0000x reference)
//
#include <hip/hip_runtime.h>

#define IN_DIM 40
#define HID 64
#define TSTEPS 500
#define NCH 4              // chains per block; 256 blocks = 1/CU, 8 waves = 2/SIMD
#define ROWB 192           // chain-row stride: 48 dwords -> broadcast reads, free 2-way
#define SLABP (NCH * ROWB) // 768 B per parity

typedef _Float16 half8 __attribute__((ext_vector_type(8)));
typedef float    f32x4 __attribute__((ext_vector_type(4)));

#define L2E  1.4426950408889634f   // log2(e); weights prescaled so acts use exp2 directly
#define L2E2 2.8853900817779268f   // 2*log2(e)

__device__ __forceinline__ float exp2_fast(float x) {
    return __builtin_amdgcn_exp2f(x);     // v_exp_f32 computes 2^x natively
}

// LDS-visibility barrier: no vmcnt drain (in-flight global prefetch survives).
__device__ __forceinline__ void block_sync_lds() {
    asm volatile("s_waitcnt lgkmcnt(0)" ::: "memory");
    __builtin_amdgcn_s_barrier();
    asm volatile("" ::: "memory");
}

// MFMA recurrence, 4 chains/block, 8 waves x 2 m-tiles (512 thr), 256 blocks (1/CU).
// 2 waves/SIMD (the r12-proven overlap) AND 4x replication (r9's economy):
// MFMA pipe time per SIMD halves vs r12. Gate-interleaved exp2-prescaled W rows;
// h stored once per chain (192B rows), replicated via broadcast-read addressing;
// one lgkm-only barrier per step; x-part computed in-step under the ds_read shadow.
__global__ __launch_bounds__(512, 1)
void lstm_mfma(const float* __restrict__ x,
               const float* __restrict__ W_ih,
               const float* __restrict__ W_hh,
               const float* __restrict__ b_ih,
               const float* __restrict__ b_hh,
               const float* __restrict__ fc1_w,
               const float* __restrict__ fc1_b,
               const float* __restrict__ fc2_w,
               const float* __restrict__ fc2_b,
               float* __restrict__ out)
{
    const int tid = threadIdx.x;
    const int w   = tid >> 6;        // wave id 0..7: m-tiles 2w, 2w+1 (units 8w..8w+7)
    const int l   = tid & 63;
    const int lr  = l & 15;          // B/D column: chain = lr&3, replica = lr>>2
    const int lg  = l >> 4;          // k-group / D-row group
    const int ch  = lr & 3;          // this lane's chain
    const int jj  = (lr >> 2) & 1;   // owned tile select (valid for owners lr<8)
    const bool own = (lr < 8);       // owner lanes: replica 0/1 -> tiles 0/1
    const int blk = blockIdx.x;

    __shared__ __align__(16) unsigned char slab[2 * SLABP];   // 1536 B, parity dbuf
    __shared__ float h32[NCH][HID];
    __shared__ float rl [NCH][HID];

    // ---- zero slab parity 0 (h0 = 0): 768 B = 48 x uint4 ----
    if (tid < SLABP / 16) reinterpret_cast<uint4*>(slab)[tid] = uint4{0, 0, 0, 0};

    // ---- persistent A-fragments: 2 tiles x 4 k-tiles (gate-interleaved, prescaled) ----
    half8 wfrag[2][4];               // 32 VGPRs
    #pragma unroll
    for (int j = 0; j < 2; ++j) {
        const int jt   = 2 * w + j;
        const int unit = 4 * jt + (lr >> 2);
        const int gate = lr & 3;
        const int row  = gate * HID + unit;
        const float sc = (gate == 2) ? L2E2 : L2E;   // tanh rows get 2log2e
        #pragma unroll
        for (int kt = 0; kt < 4; ++kt) {
            const int k0 = kt * 32 + lg * 8;
            float v[8];
            if (k0 < 64) {
                const float4* p = reinterpret_cast<const float4*>(W_hh + (size_t)row * HID + k0);
                float4 q0 = p[0], q1 = p[1];
                v[0]=q0.x; v[1]=q0.y; v[2]=q0.z; v[3]=q0.w;
                v[4]=q1.x; v[5]=q1.y; v[6]=q1.z; v[7]=q1.w;
            } else if (k0 < 104) {
                const float4* p = reinterpret_cast<const float4*>(W_ih + (size_t)row * IN_DIM + (k0 - 64));
                float4 q0 = p[0], q1 = p[1];
                v[0]=q0.x; v[1]=q0.y; v[2]=q0.z; v[3]=q0.w;
                v[4]=q1.x; v[5]=q1.y; v[6]=q1.z; v[7]=q1.w;
            } else {
                #pragma unroll
                for (int e = 0; e < 8; ++e) v[e] = 0.0f;
            }
            half8 hv;
            #pragma unroll
            for (int e = 0; e < 8; ++e) hv[e] = (_Float16)(v[e] * sc);
            wfrag[j][kt] = hv;
        }
    }

    // ---- per-lane bias for the single owned cell ----
    const int uown = 8 * w + 4 * jj + lg;   // unit of this lane's cell (owners)
    const f32x4 biasown = {
        (b_ih[0 * HID + uown] + b_hh[0 * HID + uown]) * L2E,
        (b_ih[1 * HID + uown] + b_hh[1 * HID + uown]) * L2E,
        (b_ih[2 * HID + uown] + b_hh[2 * HID + uown]) * L2E2,
        (b_ih[3 * HID + uown] + b_hh[3 * HID + uown]) * L2E };

    // ---- per-lane x addresses: chain ch; kt=2 elems lg*8..+7, kt=3 elems 32..39 ----
    const float* xrow = x + ((size_t)(blk * NCH + ch) * TSTEPS) * IN_DIM;
    const float* xg2  = xrow + lg * 8;
    const float* xg3  = xrow + 32;      // kt=3: A-rows beyond k=40 are zero (pad)

    // single x register buffer: holds x_t at the top of step t
    float4 xb0 = *reinterpret_cast<const float4*>(xg2);
    float4 xb1 = *reinterpret_cast<const float4*>(xg2 + 4);
    float4 xb2 = *reinterpret_cast<const float4*>(xg3);
    float4 xb3 = *reinterpret_cast<const float4*>(xg3 + 4);

    __syncthreads();   // one-time full drain (slab zero + x_0 visible)

    float cs = 0.0f;   // ONE cell per owner lane: (chain ch, unit uown)

    auto step = [&](int t, int par, bool lastt) {
        // 1. issue h B-frag reads (broadcast; 16 lines/instr, 2 lines/bank = free)
        const unsigned char* sb = slab + par * SLABP + ch * ROWB;
        uint4 q0 = *reinterpret_cast<const uint4*>(sb + lg * 16);
        uint4 q1 = *reinterpret_cast<const uint4*>(sb + 64 + lg * 16);
        // 2. under the ds_read shadow: convert x_t, x-part MFMAs for both tiles
        half8 xf2 = { (_Float16)xb0.x, (_Float16)xb0.y, (_Float16)xb0.z, (_Float16)xb0.w,
                      (_Float16)xb1.x, (_Float16)xb1.y, (_Float16)xb1.z, (_Float16)xb1.w };
        half8 xf3 = { (_Float16)xb2.x, (_Float16)xb2.y, (_Float16)xb2.z, (_Float16)xb2.w,
                      (_Float16)xb3.x, (_Float16)xb3.y, (_Float16)xb3.z, (_Float16)xb3.w };
        f32x4 xacc[2];
        #pragma unroll
        for (int j = 0; j < 2; ++j) {
            f32x4 a = f32x4{0.0f, 0.0f, 0.0f, 0.0f};
            a = __builtin_amdgcn_mfma_f32_16x16x32_f16(wfrag[j][2], xf2, a, 0, 0, 0);
            a = __builtin_amdgcn_mfma_f32_16x16x32_f16(wfrag[j][3], xf3, a, 0, 0, 0);
            xacc[j] = a;
        }
        // 3. x_t consumed -> issue x_{t+1} prefetch (in flight across the barrier)
        {
            const size_t toff = (size_t)((t + 1 < TSTEPS) ? t + 1 : TSTEPS - 1) * IN_DIM;
            xb0 = *reinterpret_cast<const float4*>(xg2 + toff);
            xb1 = *reinterpret_cast<const float4*>(xg2 + toff + 4);
            xb2 = *reinterpret_cast<const float4*>(xg3 + toff);
            xb3 = *reinterpret_cast<const float4*>(xg3 + toff + 4);
        }
        // 4. h MFMAs (depth-2 on xacc) + owner tile select (4 cndmask)
        half8 bf0 = __builtin_bit_cast(half8, q0);   // compiler inserts lgkm wait here
        half8 bf1 = __builtin_bit_cast(half8, q1);
        f32x4 z0a, z1a;
        {
            f32x4 a = __builtin_amdgcn_mfma_f32_16x16x32_f16(wfrag[0][0], bf0, xacc[0], 0, 0, 0);
            z0a = __builtin_amdgcn_mfma_f32_16x16x32_f16(wfrag[0][1], bf1, a, 0, 0, 0);
            f32x4 b = __builtin_amdgcn_mfma_f32_16x16x32_f16(wfrag[1][0], bf0, xacc[1], 0, 0, 0);
            z1a = __builtin_amdgcn_mfma_f32_16x16x32_f16(wfrag[1][1], bf1, b, 0, 0, 0);
        }
        const bool m1 = (jj == 1);
        float z0 = (m1 ? z1a[0] : z0a[0]) + biasown[0];
        float z1 = (m1 ? z1a[1] : z0a[1]) + biasown[1];
        float z2 = (m1 ? z1a[2] : z0a[2]) + biasown[2];
        float z3 = (m1 ? z1a[3] : z0a[3]) + biasown[3];
        // 5. exp2-direct activations (z prescaled by log2e / 2log2e)
        float iv = __builtin_amdgcn_rcpf(1.0f + exp2_fast(-z0));
        float fv = __builtin_amdgcn_rcpf(1.0f + exp2_fast(-z1));
        float ov = __builtin_amdgcn_rcpf(1.0f + exp2_fast(-z3));
        float e2 = exp2_fast(-fabsf(z2));
        float gv = copysignf((1.0f - e2) * __builtin_amdgcn_rcpf(1.0f + e2), z2);
        cs = fmaf(fv, cs, iv * gv);
        float ec = exp2_fast(-fabsf(cs * L2E2));
        float h  = ov * copysignf((1.0f - ec) * __builtin_amdgcn_rcpf(1.0f + ec), cs);
        // 6. owner lanes publish h once (2-way b16 aliasing = free)
        if (lastt) {
            if (own) h32[ch][uown] = h;
        } else if (own) {
            unsigned char* db = slab + (par ^ 1) * SLABP + ch * ROWB + uown * 2;
            _Float16 hf = (_Float16)h;
            *reinterpret_cast<unsigned short*>(db) = __builtin_bit_cast(unsigned short, hf);
        }
        // 7. the only per-step barrier (lgkmcnt only; global prefetch stays in flight)
        block_sync_lds();
    };

    #pragma unroll 1
    for (int t = 0; t < TSTEPS; t += 2) {
        step(t,     0, false);
        step(t + 1, 1, t + 1 == TSTEPS - 1);
    }

    // ---- epilogue: fc1 + relu (waves 0..3 -> chains 0..3), then fc2 ----
    if (w < NCH) {
        float acc = fc1_b[l];
        const float4* fwp = reinterpret_cast<const float4*>(fc1_w + (size_t)l * HID);
        #pragma unroll
        for (int q = 0; q < 16; ++q) {
            float4 wv = fwp[q];
            float4 hv = reinterpret_cast<const float4*>(&h32[w][0])[q];
            acc = fmaf(wv.x, hv.x, acc);
            acc = fmaf(wv.y, hv.y, acc);
            acc = fmaf(wv.z, hv.z, acc);
            acc = fmaf(wv.w, hv.w, acc);
        }
        rl[w][l] = fmaxf(acc, 0.0f);
    }
    __syncthreads();
    if (tid < NCH * 2) {
        const int c = tid >> 1;
        const int o = tid & 1;
        float acc = fc2_b[o];
        for (int k = 0; k < HID; ++k)
            acc = fmaf(fc2_w[o * HID + k], rl[c][k], acc);
        out[(size_t)(blk * NCH + c) * 2 + o] = acc;
    }
}

extern "C" void kernel_launch(void* const* d_in, const int* in_sizes, int n_in,
                              void* d_out, int out_size, void* d_ws, size_t ws_size,
                              hipStream_t stream) {
    const float* x     = (const float*)d_in[0];
    const float* W_ih  = (const float*)d_in[1];
    const float* W_hh  = (const float*)d_in[2];
    const float* b_ih  = (const float*)d_in[3];
    const float* b_hh  = (const float*)d_in[4];
    const float* fc1_w = (const float*)d_in[5];
    const float* fc1_b = (const float*)d_in[6];
    const float* fc2_w = (const float*)d_in[7];
    const float* fc2_b = (const float*)d_in[8];
    float* out = (float*)d_out;

    const int B = in_sizes[0] / (TSTEPS * IN_DIM);   // 1024
    lstm_mfma<<<B / NCH, 512, 0, stream>>>(x, W_ih, W_hh, b_ih, b_hh,
                                           fc1_w, fc1_b, fc2_w, fc2_b, out);
}

// Round 15
// 251.383 us; speedup vs baseline: 2.1114x; 2.1114x over previous
//
#include <hip/hip_runtime.h>

#define IN_DIM 40
#define HID 64
#define TSTEPS 500
#define NCH 2              // chains per block; 512 blocks -> 2 independent blocks/CU
#define ROWB 192           // chain-row stride: 48 dwords === 16 (mod 32) -> broadcast reads conflict-free
#define SLABP (NCH * ROWB) // 384 B per parity

typedef _Float16 half8 __attribute__((ext_vector_type(8)));
typedef float    f32x4 __attribute__((ext_vector_type(4)));

#define L2E  1.4426950408889634f   // log2(e); weights prescaled so acts use exp2 directly
#define L2E2 2.8853900817779268f   // 2*log2(e)

__device__ __forceinline__ float exp2_fast(float x) {
    return __builtin_amdgcn_exp2f(x);     // v_exp_f32 computes 2^x natively
}

// LDS-visibility barrier: no vmcnt drain (in-flight global prefetch survives).
__device__ __forceinline__ void block_sync_lds() {
    asm volatile("s_waitcnt lgkmcnt(0)" ::: "memory");
    __builtin_amdgcn_s_barrier();
    asm volatile("" ::: "memory");
}

// MFMA recurrence, 2 chains/block (512 blocks = 2/CU for latency interleave), 4 waves.
// W rows gate-interleaved; sigmoid rows prescaled by log2e, tanh-gate rows by 2log2e,
// so activations are exp2-direct. Both tanh evaluations use 2*sigmoid(2x)-1 (no
// abs/copysign; exact saturation at both ends). h stored once per chain (192B rows),
// replicated via broadcast-read addressing. One lgkm-only barrier per step.
__global__ __launch_bounds__(256, 2)
void lstm_mfma(const float* __restrict__ x,
               const float* __restrict__ W_ih,
               const float* __restrict__ W_hh,
               const float* __restrict__ b_ih,
               const float* __restrict__ b_hh,
               const float* __restrict__ fc1_w,
               const float* __restrict__ fc1_b,
               const float* __restrict__ fc2_w,
               const float* __restrict__ fc2_b,
               float* __restrict__ out)
{
    const int tid = threadIdx.x;
    const int w   = tid >> 6;        // wave id: m-tiles 4w..4w+3 (units 16w..16w+15)
    const int l   = tid & 63;
    const int lr  = l & 15;          // B/D column
    const int lg  = l >> 4;          // k-group / D-row group
    const int ch  = lr & 1;          // this lane's chain
    const int jj  = lr >> 1;         // owner m-tile select (valid for lr<8)
    const bool own = (lr < 8);       // cell-owner lanes
    const int blk = blockIdx.x;

    __shared__ __align__(16) unsigned char slab[2 * SLABP];   // 768 B, parity dbuf
    __shared__ float h32[NCH][HID];
    __shared__ float rl [NCH][HID];

    // ---- zero slab parity 0 (h0 = 0): 384 B = 24 x uint4 ----
    if (tid < SLABP / 16) reinterpret_cast<uint4*>(slab)[tid] = uint4{0, 0, 0, 0};

    // ---- persistent A-fragments (gate-interleaved rows, exp2-prescaled) + biases ----
    half8 wfrag[4][4];
    f32x4 biasr[4];
    #pragma unroll
    for (int j = 0; j < 4; ++j) {
        const int jt   = 4 * w + j;
        const int unit = 4 * jt + (lr >> 2);
        const int gate = lr & 3;
        const int row  = gate * HID + unit;
        const float sc = (gate == 2) ? L2E2 : L2E;   // tanh rows get 2log2e
        #pragma unroll
        for (int kt = 0; kt < 4; ++kt) {
            const int k0 = kt * 32 + lg * 8;
            float v[8];
            if (k0 < 64) {
                const float4* p = reinterpret_cast<const float4*>(W_hh + (size_t)row * HID + k0);
                float4 q0 = p[0], q1 = p[1];
                v[0]=q0.x; v[1]=q0.y; v[2]=q0.z; v[3]=q0.w;
                v[4]=q1.x; v[5]=q1.y; v[6]=q1.z; v[7]=q1.w;
            } else if (k0 < 104) {
                const float4* p = reinterpret_cast<const float4*>(W_ih + (size_t)row * IN_DIM + (k0 - 64));
                float4 q0 = p[0], q1 = p[1];
                v[0]=q0.x; v[1]=q0.y; v[2]=q0.z; v[3]=q0.w;
                v[4]=q1.x; v[5]=q1.y; v[6]=q1.z; v[7]=q1.w;
            } else {
                #pragma unroll
                for (int e = 0; e < 8; ++e) v[e] = 0.0f;
            }
            half8 hv;
            #pragma unroll
            for (int e = 0; e < 8; ++e) hv[e] = (_Float16)(v[e] * sc);
            wfrag[j][kt] = hv;
        }
        const int ud = 4 * jt + lg;
        biasr[j] = f32x4{ (b_ih[0 * HID + ud] + b_hh[0 * HID + ud]) * L2E,
                          (b_ih[1 * HID + ud] + b_hh[1 * HID + ud]) * L2E,
                          (b_ih[2 * HID + ud] + b_hh[2 * HID + ud]) * L2E2,
                          (b_ih[3 * HID + ud] + b_hh[3 * HID + ud]) * L2E };
    }

    // ---- per-lane x addresses: chain ch; kt=2 elems lg*8..+7, kt=3 elems 32..39 ----
    const float* xrow = x + ((size_t)(blk * NCH + ch) * TSTEPS) * IN_DIM;
    const float* xg2  = xrow + lg * 8;
    const float* xg3  = xrow + 32;      // kt=3: only k<40 A-rows nonzero (pad zeroed)

    // ---- prologue: xacc for t=0 from x_0; prefetch x_1 ----
    f32x4 xaccA[4], xaccB[4];
    {
        float4 p0 = *reinterpret_cast<const float4*>(xg2);
        float4 p1 = *reinterpret_cast<const float4*>(xg2 + 4);
        float4 p2 = *reinterpret_cast<const float4*>(xg3);
        float4 p3 = *reinterpret_cast<const float4*>(xg3 + 4);
        half8 xf2 = { (_Float16)p0.x, (_Float16)p0.y, (_Float16)p0.z, (_Float16)p0.w,
                      (_Float16)p1.x, (_Float16)p1.y, (_Float16)p1.z, (_Float16)p1.w };
        half8 xf3 = { (_Float16)p2.x, (_Float16)p2.y, (_Float16)p2.z, (_Float16)p2.w,
                      (_Float16)p3.x, (_Float16)p3.y, (_Float16)p3.z, (_Float16)p3.w };
        #pragma unroll
        for (int j = 0; j < 4; ++j) {
            f32x4 a = biasr[j];
            a = __builtin_amdgcn_mfma_f32_16x16x32_f16(wfrag[j][2], xf2, a, 0, 0, 0);
            a = __builtin_amdgcn_mfma_f32_16x16x32_f16(wfrag[j][3], xf3, a, 0, 0, 0);
            xaccA[j] = a;
        }
    }
    float4 rA0 = *reinterpret_cast<const float4*>(xg2 + IN_DIM);
    float4 rA1 = *reinterpret_cast<const float4*>(xg2 + IN_DIM + 4);
    float4 rA2 = *reinterpret_cast<const float4*>(xg3 + IN_DIM);
    float4 rA3 = *reinterpret_cast<const float4*>(xg3 + IN_DIM + 4);
    float4 rB0, rB1, rB2, rB3;

    __syncthreads();   // one-time full drain (slab zero visible)

    float cs = 0.0f;   // ONE cell per owner lane: (chain ch, unit uown)
    const int uown = 16 * w + 4 * (jj & 3) + lg;

    auto step = [&](int t, int par, f32x4 (&xacc)[4], f32x4 (&xnxt)[4],
                    const float4& c0, const float4& c1, const float4& c2, const float4& c3,
                    float4& n0, float4& n1, float4& n2, float4& n3) {
        const bool lastt = (t == TSTEPS - 1);
        // 1. h B-frags: broadcast read of row ch (conflict-free; 8-lane broadcast/line)
        const unsigned char* sb = slab + par * SLABP + ch * ROWB;
        uint4 q0 = *reinterpret_cast<const uint4*>(sb + lg * 16);
        uint4 q1 = *reinterpret_cast<const uint4*>(sb + 64 + lg * 16);
        // 2. issue x_{t+2} prefetch (used next step, off-path)
        {
            const size_t toff = (size_t)((t + 2 < TSTEPS) ? t + 2 : TSTEPS - 1) * IN_DIM;
            n0 = *reinterpret_cast<const float4*>(xg2 + toff);
            n1 = *reinterpret_cast<const float4*>(xg2 + toff + 4);
            n2 = *reinterpret_cast<const float4*>(xg3 + toff);
            n3 = *reinterpret_cast<const float4*>(xg3 + toff + 4);
        }
        // ---- critical chain: boost priority (other block's waves yield) ----
        __builtin_amdgcn_s_setprio(1);
        // 3. h MFMAs: depth-2 chain on top of precomputed xacc
        half8 bf0 = __builtin_bit_cast(half8, q0);
        half8 bf1 = __builtin_bit_cast(half8, q1);
        f32x4 acc[4];
        #pragma unroll
        for (int j = 0; j < 4; ++j) {
            f32x4 a = xacc[j];
            a = __builtin_amdgcn_mfma_f32_16x16x32_f16(wfrag[j][0], bf0, a, 0, 0, 0);
            a = __builtin_amdgcn_mfma_f32_16x16x32_f16(wfrag[j][1], bf1, a, 0, 0, 0);
            acc[j] = a;
        }
        // 4. select this lane's cell (jj) without runtime indexing
        float z0, z1, z2, z3;
        {
            float t01, t23;
            t01 = (jj & 1) ? acc[1][0] : acc[0][0];
            t23 = (jj & 1) ? acc[3][0] : acc[2][0];
            z0  = (jj & 2) ? t23 : t01;
            t01 = (jj & 1) ? acc[1][1] : acc[0][1];
            t23 = (jj & 1) ? acc[3][1] : acc[2][1];
            z1  = (jj & 2) ? t23 : t01;
            t01 = (jj & 1) ? acc[1][2] : acc[0][2];
            t23 = (jj & 1) ? acc[3][2] : acc[2][2];
            z2  = (jj & 2) ? t23 : t01;
            t01 = (jj & 1) ? acc[1][3] : acc[0][3];
            t23 = (jj & 1) ? acc[3][3] : acc[2][3];
            z3  = (jj & 2) ? t23 : t01;
        }
        // 5. activations, exp2-direct; tanh via 2*sigmoid(2x)-1 (no abs/copysign)
        float iv = __builtin_amdgcn_rcpf(1.0f + exp2_fast(-z0));
        float fv = __builtin_amdgcn_rcpf(1.0f + exp2_fast(-z1));
        float ov = __builtin_amdgcn_rcpf(1.0f + exp2_fast(-z3));
        float gv = fmaf(2.0f, __builtin_amdgcn_rcpf(1.0f + exp2_fast(-z2)), -1.0f);
        cs = fmaf(fv, cs, iv * gv);
        float th = fmaf(2.0f, __builtin_amdgcn_rcpf(1.0f + exp2_fast(-(cs * L2E2))), -1.0f);
        float h  = ov * th;
        // 6. owner lanes publish h ONCE
        if (lastt) {
            if (own) h32[ch][uown] = h;
        } else if (own) {
            unsigned char* db = slab + (par ^ 1) * SLABP + ch * ROWB + uown * 2;
            _Float16 hf = (_Float16)h;
            *reinterpret_cast<unsigned short*>(db) = __builtin_bit_cast(unsigned short, hf);
        }
        __builtin_amdgcn_s_setprio(0);
        // 7. precompute next step's x-part (off-path; vmcnt wait lands here)
        {
            half8 xf2 = { (_Float16)c0.x, (_Float16)c0.y, (_Float16)c0.z, (_Float16)c0.w,
                          (_Float16)c1.x, (_Float16)c1.y, (_Float16)c1.z, (_Float16)c1.w };
            half8 xf3 = { (_Float16)c2.x, (_Float16)c2.y, (_Float16)c2.z, (_Float16)c2.w,
                          (_Float16)c3.x, (_Float16)c3.y, (_Float16)c3.z, (_Float16)c3.w };
            #pragma unroll
            for (int j = 0; j < 4; ++j) {
                f32x4 a = biasr[j];
                a = __builtin_amdgcn_mfma_f32_16x16x32_f16(wfrag[j][2], xf2, a, 0, 0, 0);
                a = __builtin_amdgcn_mfma_f32_16x16x32_f16(wfrag[j][3], xf3, a, 0, 0, 0);
                xnxt[j] = a;
            }
        }
        // 8. the only per-step barrier (lgkmcnt only; global prefetch stays in flight)
        block_sync_lds();
    };

    #pragma unroll 1
    for (int t = 0; t < TSTEPS; t += 2) {
        step(t,     0, xaccA, xaccB, rA0, rA1, rA2, rA3, rB0, rB1, rB2, rB3);
        step(t + 1, 1, xaccB, xaccA, rB0, rB1, rB2, rB3, rA0, rA1, rA2, rA3);
    }

    // ---- epilogue: fc1 + relu (waves 0,1 -> chains 0,1), then fc2 ----
    if (w < NCH) {
        float acc = fc1_b[l];
        const float4* fwp = reinterpret_cast<const float4*>(fc1_w + (size_t)l * HID);
        #pragma unroll
        for (int q = 0; q < 16; ++q) {
            float4 wv = fwp[q];
            float4 hv = reinterpret_cast<const float4*>(&h32[w][0])[q];
            acc = fmaf(wv.x, hv.x, acc);
            acc = fmaf(wv.y, hv.y, acc);
            acc = fmaf(wv.z, hv.z, acc);
            acc = fmaf(wv.w, hv.w, acc);
        }
        rl[w][l] = fmaxf(acc, 0.0f);
    }
    __syncthreads();
    if (tid < NCH * 2) {
        const int c = tid >> 1;
        const int o = tid & 1;
        float acc = fc2_b[o];
        for (int k = 0; k < HID; ++k)
            acc = fmaf(fc2_w[o * HID + k], rl[c][k], acc);
        out[(size_t)(blk * NCH + c) * 2 + o] = acc;
    }
}

extern "C" void kernel_launch(void* const* d_in, const int* in_sizes, int n_in,
                              void* d_out, int out_size, void* d_ws, size_t ws_size,
                              hipStream_t stream) {
    const float* x     = (const float*)d_in[0];
    const float* W_ih  = (const float*)d_in[1];
    const float* W_hh  = (const float*)d_in[2];
    const float* b_ih  = (const float*)d_in[3];
    const float* b_hh  = (const float*)d_in[4];
    const float* fc1_w = (const float*)d_in[5];
    const float* fc1_b = (const float*)d_in[6];
    const float* fc2_w = (const float*)d_in[7];
    const float* fc2_b = (const float*)d_in[8];
    float* out = (float*)d_out;

    const int B = in_sizes[0] / (TSTEPS * IN_DIM);   // 1024
    lstm_mfma<<<B / NCH, 256, 0, stream>>>(x, W_ih, W_hh, b_ih, b_hh,
                                           fc1_w, fc1_b, fc2_w, fc2_b, out);
}